// Round 1
// baseline (1283.258 us; speedup 1.0000x reference)
//
#include <hip/hip_runtime.h>
#include <stdint.h>

#define TOK 8192
#define EMBD 1024
#define HIDD 4096
#define NEXP 8

typedef _Float16 f16;
typedef _Float16 f16x8 __attribute__((ext_vector_type(8)));
typedef _Float16 f16x4 __attribute__((ext_vector_type(4)));
typedef float f32x4 __attribute__((ext_vector_type(4)));
typedef unsigned short u16;
typedef unsigned short u16x4 __attribute__((ext_vector_type(4)));

// ---------------- static workspace arena ----------------
constexpr size_t OFF_X16   = 0;                                      // [TOK][EMBD] f16
constexpr size_t OFF_RW1T  = OFF_X16  + (size_t)TOK*EMBD*2;          // [HIDD][EMBD] f16
constexpr size_t OFF_W1T   = OFF_RW1T + (size_t)HIDD*EMBD*2;         // [E][HIDD][EMBD] f16
constexpr size_t OFF_W2T   = OFF_W1T  + (size_t)NEXP*HIDD*EMBD*2;    // [E][EMBD][HIDD] f16
constexpr size_t OFF_HR    = OFF_W2T  + (size_t)NEXP*EMBD*HIDD*2;    // [TOK][HIDD] f16
constexpr size_t OFF_XG    = OFF_HR   + (size_t)TOK*HIDD*2;          // [2T+128][EMBD] f16
constexpr size_t OFF_HG    = OFF_XG   + (size_t)(2*TOK+128)*EMBD*2;  // [2T+128][HIDD] f16
constexpr size_t OFF_YG    = OFF_HG   + (size_t)(2*TOK+128)*HIDD*2;  // [2T][EMBD] f16
constexpr size_t OFF_XF    = OFF_YG   + (size_t)2*TOK*EMBD*2;        // [512][EMBD] f32
constexpr size_t OFF_HF    = OFF_XF   + 512UL*EMBD*4;                // [512][HIDD] f32
constexpr size_t OFF_KIDX  = OFF_HF   + 512UL*HIDD*4;                // [2T] int
constexpr size_t OFF_KW    = OFF_KIDX + 2UL*TOK*4;                   // [2T] f32
constexpr size_t OFF_RMAP  = OFF_KW   + 2UL*TOK*4;                   // [2T] int
constexpr size_t OFF_FLAG  = OFF_RMAP + 2UL*TOK*4;                   // [512] int
constexpr size_t OFF_MISC  = OFF_FLAG + 512UL*4;                     // counts[8],offs[9]@8,cur[8]@20,nf@30
constexpr size_t WS_TOTAL  = OFF_MISC + 1024;

__device__ __align__(1024) unsigned char g_ws[WS_TOTAL];

__device__ __forceinline__ u16 f2h(float f) {
  f16 h = (f16)f;
  return __builtin_bit_cast(u16, h);
}

__device__ __forceinline__ void async_cp16(const void* g, void* l) {
  __builtin_amdgcn_global_load_lds((const __attribute__((address_space(1))) void*)g,
                                   (__attribute__((address_space(3))) void*)l, 16, 0, 0);
}

// ---------------- small utility kernels ----------------
__global__ void k_init() {
  int* misc = (int*)(g_ws + OFF_MISC);
  if (threadIdx.x < 32) misc[threadIdx.x] = 0;
}

__global__ void k_cvt_x(const float* __restrict__ x) {
  u16* X16 = (u16*)(g_ws + OFF_X16);
  int i = (blockIdx.x * 256 + threadIdx.x) * 4;
  float4 v = *(const float4*)(x + i);
  u16x4 o;
  o[0] = f2h(v.x); o[1] = f2h(v.y); o[2] = f2h(v.z); o[3] = f2h(v.w);
  *(u16x4*)(X16 + i) = o;
}

// in: fp32 [R][C] row-major, out: f16 [C][R] row-major (per blockIdx.z matrix)
__global__ void k_transpose(const float* __restrict__ in, size_t offOut, int R, int C) {
  u16* out = (u16*)(g_ws + offOut);
  __shared__ u16 t[64][65];
  int r0 = blockIdx.y * 64, c0 = blockIdx.x * 64;
  size_t mb = (size_t)blockIdx.z * R * C;
  in += mb; out += mb;
  int tid = threadIdx.x;
#pragma unroll
  for (int i = 0; i < 16; ++i) {
    int lin = i * 256 + tid;
    int r = lin >> 6, c = lin & 63;
    t[c][r] = f2h(in[(size_t)(r0 + r) * C + c0 + c]);
  }
  __syncthreads();
#pragma unroll
  for (int i = 0; i < 16; ++i) {
    int lin = i * 256 + tid;
    int cc = lin >> 6, rr = lin & 63;
    out[(size_t)(c0 + cc) * R + r0 + rr] = t[cc][rr];
  }
}

// ---------------- main fp16 MFMA GEMM (m97-style 128x128, BK=32) ----------------
// C[M][N](f16) = act(A[M][K](f16) @ BT[N][K](f16)^T + bias[N]); grouped over experts via offs.
template <bool SILU, bool GROUPED>
__global__ __launch_bounds__(256) void gemm_f16(size_t offA, size_t offB,
                                                const float* __restrict__ bias,
                                                size_t offC, int Mfix, int N, int K) {
  const u16* A  = (const u16*)(g_ws + offA);
  const u16* BT = (const u16*)(g_ws + offB);
  u16* C = (u16*)(g_ws + offC);
  const int* offs = (const int*)(g_ws + OFF_MISC) + 8;

  int e = GROUPED ? blockIdx.z : 0;
  int rbase = GROUPED ? offs[e] : 0;
  int Me = GROUPED ? (offs[e + 1] - rbase) : Mfix;
  int m0 = blockIdx.y * 128;
  if (m0 >= Me) return;
  int n0 = blockIdx.x * 128;
  const u16* Be = BT + (size_t)e * N * K;
  const float* be = bias + (size_t)e * N;

  __shared__ u16 As[128 * 32];
  __shared__ u16 Bs[128 * 32];

  int tid = threadIdx.x;
  int lane = tid & 63, w = tid >> 6;
  int wr = w >> 1, wc = w & 1;
  int lr = lane >> 2;          // row within 16-row chunk
  int lk = (lane & 3) * 8;     // k element offset
  int rsel = lane & 15;
  int ksel = (lane >> 4) * 8;

  f32x4 acc[4][4] = {};

  for (int k0 = 0; k0 < K; k0 += 32) {
#pragma unroll
    for (int j = 0; j < 2; ++j) {
      int chunk = w * 2 + j;
      int r = m0 + chunk * 16 + lr;
      if (GROUPED) r = (r < Me) ? r : (Me - 1);  // clamp staging rows
      async_cp16(A + (size_t)(rbase + r) * K + k0 + lk, &As[chunk * 512]);
      int nr = n0 + chunk * 16 + lr;
      async_cp16(Be + (size_t)nr * K + k0 + lk, &Bs[chunk * 512]);
    }
    __syncthreads();
    f16x8 af[4], bf[4];
#pragma unroll
    for (int i = 0; i < 4; ++i)
      af[i] = *(const f16x8*)&As[(wr * 64 + i * 16 + rsel) * 32 + ksel];
#pragma unroll
    for (int j = 0; j < 4; ++j)
      bf[j] = *(const f16x8*)&Bs[(wc * 64 + j * 16 + rsel) * 32 + ksel];
#pragma unroll
    for (int i = 0; i < 4; ++i)
#pragma unroll
      for (int j = 0; j < 4; ++j)
        acc[i][j] = __builtin_amdgcn_mfma_f32_16x16x32_f16(af[i], bf[j], acc[i][j], 0, 0, 0);
    __syncthreads();
  }

  int rg = lane >> 4;
#pragma unroll
  for (int j = 0; j < 4; ++j) {
    int n = n0 + wc * 64 + j * 16 + rsel;
    float bn = be[n];
#pragma unroll
    for (int i = 0; i < 4; ++i) {
#pragma unroll
      for (int r = 0; r < 4; ++r) {
        int ml = wr * 64 + i * 16 + rg * 4 + r;
        if (m0 + ml < Me) {
          float v = acc[i][j][r] + bn;
          if (SILU) v = v / (1.0f + __expf(-v));
          C[(size_t)(rbase + m0 + ml) * N + n] = f2h(v);
        }
      }
    }
  }
}

// ---------------- router logits + top2 + margin flagging ----------------
__global__ void k_router(const float* __restrict__ rw2, const float* __restrict__ rb2,
                         const float* __restrict__ x) {
  const u16* HR = (const u16*)(g_ws + OFF_HR);
  int* kidx = (int*)(g_ws + OFF_KIDX);
  float* kw = (float*)(g_ws + OFF_KW);
  int* flag = (int*)(g_ws + OFF_FLAG);
  float* XF = (float*)(g_ws + OFF_XF);
  int* misc = (int*)(g_ws + OFF_MISC);

  int t = blockIdx.x, tid = threadIdx.x;
  int lane = tid & 63, w = tid >> 6;
  float acc[8] = {};
  const u16* hrow = HR + (size_t)t * HIDD;
#pragma unroll
  for (int i = 0; i < 2; ++i) {
    int base = i * 2048 + tid * 8;
    f16x8 v = *(const f16x8*)&hrow[base];
#pragma unroll
    for (int jj = 0; jj < 8; ++jj) {
      float hv = (float)v[jj];
      const float* r2 = rw2 + (size_t)(base + jj) * 8;
#pragma unroll
      for (int e2 = 0; e2 < 8; ++e2) acc[e2] += hv * r2[e2];
    }
  }
#pragma unroll
  for (int m = 1; m < 64; m <<= 1)
#pragma unroll
    for (int e2 = 0; e2 < 8; ++e2) acc[e2] += __shfl_xor(acc[e2], m);

  __shared__ float red[4][8];
  __shared__ int s_fi;
  if (lane == 0)
    for (int e2 = 0; e2 < 8; ++e2) red[w][e2] = acc[e2];
  if (tid == 0) s_fi = -1;
  __syncthreads();
  if (tid == 0) {
    float lg[8];
    for (int e2 = 0; e2 < 8; ++e2)
      lg[e2] = red[0][e2] + red[1][e2] + red[2][e2] + red[3][e2] + rb2[e2];
    int i1 = 0; float l1 = lg[0];
    for (int e2 = 1; e2 < 8; ++e2) if (lg[e2] > l1) { l1 = lg[e2]; i1 = e2; }
    int i2 = -1; float l2 = -3.4e38f;
    for (int e2 = 0; e2 < 8; ++e2) if (e2 != i1 && lg[e2] > l2) { l2 = lg[e2]; i2 = e2; }
    float l3 = -3.4e38f;
    for (int e2 = 0; e2 < 8; ++e2) if (e2 != i1 && e2 != i2 && lg[e2] > l3) l3 = lg[e2];
    float ex = __expf(l2 - l1);
    float inv = 1.0f / (1.0f + ex);
    kidx[2 * t] = i1; kidx[2 * t + 1] = i2;
    kw[2 * t] = inv;  kw[2 * t + 1] = ex * inv;
    if (l2 - l3 < 4e-3f) {  // near-tie: needs exact fp32 rescue
      int fi = atomicAdd(misc + 30, 1);
      if (fi < 512) { flag[fi] = t; s_fi = fi; }
    }
  }
  __syncthreads();
  int fi = s_fi;
  if (fi >= 0) {
    const float* xs = x + (size_t)t * EMBD;
    float* xd = XF + (size_t)fi * EMBD;
    int d = tid * 4;
    *(float4*)(xd + d) = *(const float4*)(xs + d);
  }
}

// exact fp32 router hidden for flagged tokens: HF = silu(XF @ rw1 + rb1)
__global__ __launch_bounds__(256) void k_flag_gemm(const float* __restrict__ rw1,
                                                   const float* __restrict__ rb1) {
  int* misc = (int*)(g_ws + OFF_MISC);
  int F = misc[30]; if (F > 512) F = 512;
  int m0 = blockIdx.y * 64;
  if (m0 >= F) return;
  int n0 = blockIdx.x * 64;
  const float* XF = (const float*)(g_ws + OFF_XF);
  float* HF = (float*)(g_ws + OFF_HF);
  __shared__ float As[64][17];
  __shared__ float Bs[16][65];
  int tid = threadIdx.x;
  float acc[4][4] = {};
  for (int k0 = 0; k0 < EMBD; k0 += 16) {
#pragma unroll
    for (int i = 0; i < 4; ++i) {
      int lin = i * 256 + tid;
      As[lin >> 4][lin & 15] = XF[(size_t)(m0 + (lin >> 4)) * EMBD + k0 + (lin & 15)];
      Bs[lin >> 6][lin & 63] = rw1[(size_t)(k0 + (lin >> 6)) * HIDD + n0 + (lin & 63)];
    }
    __syncthreads();
    int ty = tid >> 4, tx = tid & 15;
#pragma unroll
    for (int kk = 0; kk < 16; ++kk) {
      float a4[4], b4[4];
#pragma unroll
      for (int a = 0; a < 4; ++a) a4[a] = As[ty * 4 + a][kk];
#pragma unroll
      for (int b = 0; b < 4; ++b) b4[b] = Bs[kk][tx * 4 + b];
#pragma unroll
      for (int a = 0; a < 4; ++a)
#pragma unroll
        for (int b = 0; b < 4; ++b) acc[a][b] += a4[a] * b4[b];
    }
    __syncthreads();
  }
  int ty = tid >> 4, tx = tid & 15;
  for (int a = 0; a < 4; ++a)
    for (int b = 0; b < 4; ++b) {
      int n = n0 + tx * 4 + b;
      float v = acc[a][b] + rb1[n];
      v = v / (1.0f + __expf(-v));
      HF[(size_t)(m0 + ty * 4 + a) * HIDD + n] = v;
    }
}

__global__ void k_flag_fix(const float* __restrict__ rw2, const float* __restrict__ rb2) {
  int* misc = (int*)(g_ws + OFF_MISC);
  int F = misc[30]; if (F > 512) F = 512;
  int fi = blockIdx.x; if (fi >= F) return;
  const int* flag = (const int*)(g_ws + OFF_FLAG);
  const float* HF = (const float*)(g_ws + OFF_HF);
  int* kidx = (int*)(g_ws + OFF_KIDX);
  float* kw = (float*)(g_ws + OFF_KW);
  int t = flag[fi];
  int tid = threadIdx.x, lane = tid & 63, w = tid >> 6;
  const float* h = HF + (size_t)fi * HIDD;
  float acc[8] = {};
  for (int i = 0; i < 16; ++i) {
    int hh = i * 256 + tid;
    float hv = h[hh];
    const float* r2 = rw2 + (size_t)hh * 8;
#pragma unroll
    for (int e2 = 0; e2 < 8; ++e2) acc[e2] += hv * r2[e2];
  }
#pragma unroll
  for (int m = 1; m < 64; m <<= 1)
#pragma unroll
    for (int e2 = 0; e2 < 8; ++e2) acc[e2] += __shfl_xor(acc[e2], m);
  __shared__ float red[4][8];
  if (lane == 0)
    for (int e2 = 0; e2 < 8; ++e2) red[w][e2] = acc[e2];
  __syncthreads();
  if (tid == 0) {
    float lg[8];
    for (int e2 = 0; e2 < 8; ++e2)
      lg[e2] = red[0][e2] + red[1][e2] + red[2][e2] + red[3][e2] + rb2[e2];
    int i1 = 0; float l1 = lg[0];
    for (int e2 = 1; e2 < 8; ++e2) if (lg[e2] > l1) { l1 = lg[e2]; i1 = e2; }
    int i2 = -1; float l2 = -3.4e38f;
    for (int e2 = 0; e2 < 8; ++e2) if (e2 != i1 && lg[e2] > l2) { l2 = lg[e2]; i2 = e2; }
    float ex = __expf(l2 - l1);
    float inv = 1.0f / (1.0f + ex);
    kidx[2 * t] = i1; kidx[2 * t + 1] = i2;
    kw[2 * t] = inv;  kw[2 * t + 1] = ex * inv;
  }
}

__global__ void k_count() {
  int idx = blockIdx.x * 256 + threadIdx.x;
  if (idx < 2 * TOK) {
    int* misc = (int*)(g_ws + OFF_MISC);
    const int* kidx = (const int*)(g_ws + OFF_KIDX);
    atomicAdd(&misc[kidx[idx]], 1);
  }
}

__global__ void k_scan() {
  if (threadIdx.x == 0) {
    int* misc = (int*)(g_ws + OFF_MISC);
    int* counts = misc; int* offs = misc + 8; int* cur = misc + 20;
    offs[0] = 0;
    for (int e = 0; e < 8; ++e) { offs[e + 1] = offs[e] + counts[e]; cur[e] = offs[e]; }
  }
}

__global__ void k_build() {
  int s = blockIdx.x;
  const int* kidx = (const int*)(g_ws + OFF_KIDX);
  int* rowmap = (int*)(g_ws + OFF_RMAP);
  int* misc = (int*)(g_ws + OFF_MISC);
  const u16* X16 = (const u16*)(g_ws + OFF_X16);
  u16* XG = (u16*)(g_ws + OFF_XG);
  __shared__ int sr;
  int t = s >> 1;
  if (threadIdx.x == 0) {
    int e = kidx[s];
    sr = atomicAdd(&misc[20 + e], 1);
    rowmap[s] = sr;
  }
  __syncthreads();
  int r = sr;
  const uint4* src = (const uint4*)(X16 + (size_t)t * EMBD);
  uint4* dst = (uint4*)(XG + (size_t)r * EMBD);
  dst[threadIdx.x] = src[threadIdx.x];
  dst[threadIdx.x + 64] = src[threadIdx.x + 64];
}

__global__ void k_combine(float* __restrict__ out) {
  int t = blockIdx.x, tid = threadIdx.x;
  const int* rowmap = (const int*)(g_ws + OFF_RMAP);
  const float* kw = (const float*)(g_ws + OFF_KW);
  const u16* YG = (const u16*)(g_ws + OFF_YG);
  int r0 = rowmap[2 * t], r1 = rowmap[2 * t + 1];
  float w0 = kw[2 * t], w1 = kw[2 * t + 1];
  int d = tid * 4;
  f16x4 a = *(const f16x4*)(YG + (size_t)r0 * EMBD + d);
  f16x4 b = *(const f16x4*)(YG + (size_t)r1 * EMBD + d);
  float4 o;
  o.x = w0 * (float)a[0] + w1 * (float)b[0];
  o.y = w0 * (float)a[1] + w1 * (float)b[1];
  o.z = w0 * (float)a[2] + w1 * (float)b[2];
  o.w = w0 * (float)a[3] + w1 * (float)b[3];
  *(float4*)(out + (size_t)t * EMBD + d) = o;
}

// ---------------- launch ----------------
extern "C" void kernel_launch(void* const* d_in, const int* in_sizes, int n_in,
                              void* d_out, int out_size, void* d_ws, size_t ws_size,
                              hipStream_t stream) {
  const float* x   = (const float*)d_in[0];
  const float* rw1 = (const float*)d_in[1];
  const float* rb1 = (const float*)d_in[2];
  const float* rw2 = (const float*)d_in[3];
  const float* rb2 = (const float*)d_in[4];
  const float* w1  = (const float*)d_in[5];
  const float* b1  = (const float*)d_in[6];
  const float* w2  = (const float*)d_in[7];
  const float* b2  = (const float*)d_in[8];
  float* out = (float*)d_out;

  k_init<<<dim3(1), dim3(32), 0, stream>>>();
  k_cvt_x<<<dim3(TOK * EMBD / 1024), dim3(256), 0, stream>>>(x);
  k_transpose<<<dim3(HIDD / 64, EMBD / 64, 1), dim3(256), 0, stream>>>(rw1, OFF_RW1T, EMBD, HIDD);
  k_transpose<<<dim3(HIDD / 64, EMBD / 64, 8), dim3(256), 0, stream>>>(w1, OFF_W1T, EMBD, HIDD);
  k_transpose<<<dim3(EMBD / 64, HIDD / 64, 8), dim3(256), 0, stream>>>(w2, OFF_W2T, HIDD, EMBD);
  gemm_f16<true, false><<<dim3(HIDD / 128, TOK / 128, 1), dim3(256), 0, stream>>>(
      OFF_X16, OFF_RW1T, rb1, OFF_HR, TOK, HIDD, EMBD);
  k_router<<<dim3(TOK), dim3(256), 0, stream>>>(rw2, rb2, x);
  k_flag_gemm<<<dim3(HIDD / 64, 8), dim3(256), 0, stream>>>(rw1, rb1);
  k_flag_fix<<<dim3(512), dim3(256), 0, stream>>>(rw2, rb2);
  k_count<<<dim3(2 * TOK / 256), dim3(256), 0, stream>>>();
  k_scan<<<dim3(1), dim3(1), 0, stream>>>();
  k_build<<<dim3(2 * TOK), dim3(64), 0, stream>>>();
  gemm_f16<true, true><<<dim3(HIDD / 128, 64, 8), dim3(256), 0, stream>>>(
      OFF_XG, OFF_W1T, b1, OFF_HG, 0, HIDD, EMBD);
  gemm_f16<false, true><<<dim3(EMBD / 128, 64, 8), dim3(256), 0, stream>>>(
      OFF_HG, OFF_W2T, b2, OFF_YG, 0, EMBD, HIDD);
  k_combine<<<dim3(TOK), dim3(256), 0, stream>>>(out);
}